// Round 6
// baseline (472.837 us; speedup 1.0000x reference)
//
#include <hip/hip_runtime.h>

#define B_ 4
#define V_ 256
#define H_ 128
#define H2_ 64
#define NL_ 3
#define BV_ 1024  // B*V
#define NJQ_ 8    // j-tiles per (b,i) row-block
#define JT_ 32    // j rows per k2 block

typedef unsigned short bhalf;  // bf16 bits (internal storage; all I/O fp32)
using bf16x8 = __attribute__((ext_vector_type(8))) short;
using f32x4  = __attribute__((ext_vector_type(4))) float;

__device__ __forceinline__ float bf2f(bhalf u) {
  return __uint_as_float(((unsigned)u) << 16);
}
__device__ __forceinline__ bhalf f2bf(float f) {       // RNE (cold paths)
  unsigned u = __float_as_uint(f);
  return (bhalf)((u + 0x7FFFu + ((u >> 16) & 1u)) >> 16);
}
__device__ __forceinline__ bhalf f2bf_f(float f) {     // fast round (hot paths)
  return (bhalf)((__float_as_uint(f) + 0x8000u) >> 16);
}
__device__ __forceinline__ unsigned pack2(float a, float b) {
  return (unsigned)f2bf(a) | ((unsigned)f2bf(b) << 16);
}
__device__ __forceinline__ unsigned pack2f(float a, float b) {
  return (unsigned)f2bf_f(a) | ((unsigned)f2bf_f(b) << 16);
}
__device__ __forceinline__ void unpack8(uint4 p, float* d) {
  d[0] = bf2f((bhalf)(p.x & 0xffff)); d[1] = bf2f((bhalf)(p.x >> 16));
  d[2] = bf2f((bhalf)(p.y & 0xffff)); d[3] = bf2f((bhalf)(p.y >> 16));
  d[4] = bf2f((bhalf)(p.z & 0xffff)); d[5] = bf2f((bhalf)(p.z >> 16));
  d[6] = bf2f((bhalf)(p.w & 0xffff)); d[7] = bf2f((bhalf)(p.w >> 16));
}

// async 16B global->LDS. lds base must be wave-uniform; dest = base + lane*16.
__device__ __forceinline__ void gl2lds16(const bhalf* g, bhalf* l) {
  __builtin_amdgcn_global_load_lds(
      (const __attribute__((address_space(1))) unsigned*)g,
      (__attribute__((address_space(3))) unsigned*)l, 16, 0, 0);
}

// Keep the harness-named kernel symbol.
__global__ void VRPValueNet_66924180407123_kernel() {}

__global__ void k_init(float* out_acc) {
  if (threadIdx.x < 4) out_acc[threadIdx.x] = 0.f;
}

// ---------------- prep: UeT[l][h][k] = bf16(Ue[l][k][h]) ----------------
__global__ void __launch_bounds__(256) k_prep(const float* __restrict__ Ue,
                                              bhalf* __restrict__ UeT) {
  int l = blockIdx.x, t = threadIdx.x;
  const float* src = Ue + l * H_ * H_;
  bhalf* dst = UeT + l * H_ * H_;
#pragma unroll
  for (int it = 0; it < 64; ++it) {
    int idx = it * 256 + t;          // idx = h*128 + k
    int h = idx >> 7, k = idx & 127;
    dst[idx] = f2bf(src[k * H_ + h]);
  }
}

// ---------------- node embedding ----------------
__global__ void k0_x(const float* __restrict__ coord, const float* __restrict__ W_node,
                     const float* __restrict__ b_node, float* __restrict__ x) {
  int bi = blockIdx.x, h = threadIdx.x;
  float c0 = coord[bi * 3 + 0];
  float c1 = coord[bi * 3 + 1];
  float c2 = coord[bi * 3 + 2];
  float a = b_node[h] + c0 * W_node[h] + c1 * W_node[H_ + h] + c2 * W_node[2 * H_ + h];
  x[(size_t)bi * H_ + h] = a;
}

// ---------------- edge embedding (e bf16 row-major, uint4 stores) ----------------
__global__ void __launch_bounds__(256) k0_e(
    const float* __restrict__ xev, const float* __restrict__ xt,
    const float* __restrict__ xbt,
    const float* __restrict__ W_eval, const float* __restrict__ b_eval,
    const float* __restrict__ W_ecat, const float* __restrict__ b_ecat,
    bhalf* __restrict__ e) {
  __shared__ float w0s[H_], w1s[H_], b0s[H_];
  int bi = blockIdx.x, t = threadIdx.x;
  if (t < H_) {
    int h = t;
    if (h < H2_) { w0s[h] = W_eval[h]; w1s[h] = 0.f; b0s[h] = b_eval[h]; }
    else { int h2 = h - H2_; w0s[h] = W_ecat[h2]; w1s[h] = W_ecat[H2_ + h2]; b0s[h] = b_ecat[h2]; }
  }
  __syncthreads();
  int oct = t & 15, jt0 = t >> 4;
#pragma unroll 4
  for (int it = 0; it < 16; ++it) {
    int j = it * 16 + jt0;
    size_t ei = (size_t)bi * V_ + j;
    float v_ev = xev[ei], v_t = xt[ei], v_bt = xbt[ei];
    float vals[8];
#pragma unroll
    for (int m = 0; m < 8; ++m) {
      int h = oct * 8 + m;
      vals[m] = (h < H2_) ? (v_ev * w0s[h] + b0s[h])
                          : (v_t * w0s[h] + v_bt * w1s[h] + b0s[h]);
    }
    uint4 st;
    st.x = pack2(vals[0], vals[1]); st.y = pack2(vals[2], vals[3]);
    st.z = pack2(vals[4], vals[5]); st.w = pack2(vals[6], vals[7]);
    *(uint4*)&e[ei * H_ + oct * 8] = st;
  }
}

// ---------------- per-layer x projections: VV=(Vex,Vnx), Unx ----------------
__global__ void k1_xproj(const float* __restrict__ x,
                         const float* __restrict__ Ve, const float* __restrict__ bVe,
                         const float* __restrict__ Vn, const float* __restrict__ bVn,
                         const float* __restrict__ Un, const float* __restrict__ bUn,
                         float2* __restrict__ VV, float* __restrict__ Unx) {
  __shared__ float xs[H_];
  int bi = blockIdx.x, h = threadIdx.x;
  xs[h] = x[(size_t)bi * H_ + h];
  __syncthreads();
  float av = bVe[h], an = bVn[h], au = bUn[h];
#pragma unroll 8
  for (int k = 0; k < H_; ++k) {
    float xv = xs[k];
    av += xv * Ve[k * H_ + h];
    an += xv * Vn[k * H_ + h];
    au += xv * Un[k * H_ + h];
  }
  size_t o = (size_t)bi * H_ + h;
  VV[o] = make_float2(av, an);
  Unx[o] = au;
}

// ---------------- MFMA fused edge pass ----------------
// block = (bi, jq): 32 j-rows x 128 h. 4 waves, wave tile 16j x 64h.
// MODE 0: stage e via global_load_lds; write e_tmp + stats.
// MODE 1: stage e_new = e + relu(BN(e_tmp_prev)) via VGPRs; write e_new to
//         global AND e_tmp + stats. (fuses old k5)
// MODE 2: same staging but no e write, no e_tmp, no BN stats (last layer).
template <int MODE>
__global__ void __launch_bounds__(256, 4) k2_edge(
    bhalf* __restrict__ e, bhalf* __restrict__ et_out,
    const bhalf* __restrict__ et_prev,
    const bhalf* __restrict__ UeT_g, const float* __restrict__ bUe,
    const float2* __restrict__ VV, const float* __restrict__ mu_rs,
    const float* __restrict__ ge_prev, const float* __restrict__ be_prev,
    float* __restrict__ aggN, float* __restrict__ aggD,
    float* __restrict__ bn_ps, float* __restrict__ bn_ps2) {
  __shared__ __align__(16) bhalf UeT_s[H_ * H_];  // 32 KB; reused as red after K
  __shared__ __align__(16) bhalf es[JT_ * H_];    // 8 KB A-tile; reused as bounce

  const int t = threadIdx.x;
  const int bi = blockIdx.x >> 3;
  const int jq = blockIdx.x & 7;
  const int b = bi >> 8;
  const int lane = t & 63, w = t >> 6;
  const int c = lane & 15, q = lane >> 4;
  const int jw = w & 1, hw = w >> 1;
  const int wbase = t & 192;  // w*64

  // ---- async stage UeT (32 KB), source-XOR-swizzled ----
#pragma unroll
  for (int r = 0; r < 8; ++r) {
    int s = r * 256 + t;
    int row = s >> 4, ckL = s & 15;
    gl2lds16(UeT_g + row * H_ + (ckL ^ (row & 15)) * 8,
             &UeT_s[(size_t)(r * 256 + wbase) * 8]);
  }

  bhalf* etile = e + ((size_t)bi * V_ + jq * JT_) * H_;

  if (MODE == 0) {  // async A staging
#pragma unroll
    for (int r = 0; r < 2; ++r) {
      int s = r * 256 + t;
      int row = s >> 4, ckL = s & 15;
      gl2lds16(etile + row * H_ + (ckL ^ (row & 15)) * 8,
               &es[(size_t)(r * 256 + wbase) * 8]);
    }
  } else {  // VGPR staging with fused e-update (old k5)
    float scr[8], shr[8];
    const int ck = t & 15;
#pragma unroll
    for (int m = 0; m < 8; ++m) {
      int h = ck * 8 + m;
      float mu = mu_rs[h], rs = mu_rs[H_ + h];
      float g = ge_prev[h], bb = be_prev[h];
      scr[m] = g * rs; shr[m] = bb - g * rs * mu;
    }
    const bhalf* tprev = et_prev + ((size_t)bi * V_ + jq * JT_) * H_;
#pragma unroll
    for (int r = 0; r < 2; ++r) {
      int s = r * 256 + t;
      int row = s >> 4;
      size_t o = (size_t)row * H_ + ck * 8;
      uint4 pe = *(const uint4*)&etile[o];
      uint4 pt = *(const uint4*)&tprev[o];
      float ev[8], tv[8];
      unpack8(pe, ev); unpack8(pt, tv);
#pragma unroll
      for (int m = 0; m < 8; ++m) {
        float v = scr[m] * tv[m] + shr[m];
        if (v > 0.f) ev[m] += v;
      }
      uint4 st;
      st.x = pack2f(ev[0], ev[1]); st.y = pack2f(ev[2], ev[3]);
      st.z = pack2f(ev[4], ev[5]); st.w = pack2f(ev[6], ev[7]);
      *(uint4*)&es[row * H_ + ((ck ^ (row & 15)) * 8)] = st;
      if (MODE == 1) *(uint4*)&etile[o] = st;
    }
  }

  // ---- per-thread cvi (bUe + Vex_i) and VV_j prefetch ----
  float cvi[4];
#pragma unroll
  for (int n = 0; n < 4; ++n) {
    int h = hw * 64 + n * 16 + c;
    cvi[n] = bUe[h] + VV[(size_t)bi * H_ + h].x;
  }
  float2 vvr[4][4];
  {
    const float2* vvb = VV + ((size_t)b * V_ + jq * JT_ + jw * 16) * H_ + hw * 64;
#pragma unroll
    for (int n = 0; n < 4; ++n)
#pragma unroll
      for (int r = 0; r < 4; ++r)
        vvr[n][r] = vvb[(q * 4 + r) * H_ + n * 16 + c];
  }
  __syncthreads();  // LDS images complete

  // ---- K loop: wave tile 16j x 64h ----
  f32x4 acc[4];
#pragma unroll
  for (int n = 0; n < 4; ++n) acc[n] = {0.f, 0.f, 0.f, 0.f};
#pragma unroll
  for (int k0 = 0; k0 < 4; ++k0) {
    int kc = k0 * 4 + q;
    bf16x8 af = *(const bf16x8*)&es[(jw * 16 + c) * H_ + ((kc ^ c) * 8)];
    bf16x8 bfr[4];
#pragma unroll
    for (int n = 0; n < 4; ++n)
      bfr[n] = *(const bf16x8*)&UeT_s[(hw * 64 + n * 16 + c) * H_ + ((kc ^ c) * 8)];
#pragma unroll
    for (int n = 0; n < 4; ++n)
      acc[n] = __builtin_amdgcn_mfma_f32_16x16x32_bf16(af, bfr[n], acc[n], 0, 0, 0);
  }
  __syncthreads();  // es/UeT_s free for reuse

  // ---- epilogue ----
  float aN[4] = {0, 0, 0, 0}, aD[4] = {0, 0, 0, 0};
  float bS[4] = {0, 0, 0, 0}, bS2[4] = {0, 0, 0, 0};
#pragma unroll
  for (int n = 0; n < 4; ++n) {
#pragma unroll
    for (int r = 0; r < 4; ++r) {
      int j_ip = jw * 16 + q * 4 + r;
      int h = hw * 64 + n * 16 + c;
      float etv = acc[n][r] + cvi[n] + vvr[n][r].x;
      float g = 1.f / (1.f + __expf(-etv));
      aN[n] += g * vvr[n][r].y; aD[n] += g;
      if (MODE < 2) {
        bS[n] += etv; bS2[n] += etv * etv;
        es[j_ip * H_ + (((h >> 3) ^ (j_ip & 15)) * 8) + (h & 7)] = f2bf_f(etv);
      }
    }
  }
#pragma unroll
  for (int n = 0; n < 4; ++n) {
    aN[n] += __shfl_xor(aN[n], 16);  aN[n] += __shfl_xor(aN[n], 32);
    aD[n] += __shfl_xor(aD[n], 16);  aD[n] += __shfl_xor(aD[n], 32);
    if (MODE < 2) {
      bS[n] += __shfl_xor(bS[n], 16);  bS[n] += __shfl_xor(bS[n], 32);
      bS2[n] += __shfl_xor(bS2[n], 16); bS2[n] += __shfl_xor(bS2[n], 32);
    }
  }
  float* red = (float*)UeT_s;  // UeT_s dead after K-loop
  if (lane < 16) {
#pragma unroll
    for (int n = 0; n < 4; ++n) {
      int hl = n * 16 + c;
      red[(0 * 4 + w) * 64 + hl] = aN[n];
      red[(1 * 4 + w) * 64 + hl] = aD[n];
      if (MODE < 2) {
        red[(2 * 4 + w) * 64 + hl] = bS[n];
        red[(3 * 4 + w) * 64 + hl] = bS2[n];
      }
    }
  }
  __syncthreads();  // bounce + red images complete

  if (MODE < 2) {  // coalesced bounce -> e_tmp
#pragma unroll
    for (int it = 0; it < 2; ++it) {
      int slot = it * 256 + t;
      int jj = slot >> 4, ck = slot & 15;
      uint4 v = *(const uint4*)&es[jj * H_ + ((ck ^ (jj & 15)) * 8)];
      *(uint4*)&et_out[((size_t)bi * V_ + jq * JT_ + jj) * H_ + ck * 8] = v;
    }
  }
  if (t < H_) {
    int hw2 = t >> 6, hl = t & 63;
    int w0 = hw2 * 2, w1 = w0 + 1;
    size_t o = ((size_t)jq * BV_ + bi) * H_ + t;
    aggN[o] = red[(0 * 4 + w0) * 64 + hl] + red[(0 * 4 + w1) * 64 + hl];
    aggD[o] = red[(1 * 4 + w0) * 64 + hl] + red[(1 * 4 + w1) * 64 + hl];
    if (MODE < 2) {
      bn_ps[o]  = red[(2 * 4 + w0) * 64 + hl] + red[(2 * 4 + w1) * 64 + hl];
      bn_ps2[o] = red[(3 * 4 + w0) * 64 + hl] + red[(3 * 4 + w1) * 64 + hl];
    }
  }
}

// ---------------- merged: e-BN-stat finalize (opt) + x update ----------------
template <bool DO_E>
__global__ void __launch_bounds__(256) k34(
    const float* __restrict__ bn_ps, const float* __restrict__ bn_ps2,
    float* __restrict__ mu_rs,
    float* __restrict__ x, const float* __restrict__ Unx,
    const float* __restrict__ aggN, const float* __restrict__ aggD,
    const float* __restrict__ g_x, const float* __restrict__ bx_bn) {
  __shared__ float r1[256], r2[256];
  int h = blockIdx.x, t = threadIdx.x;
  if (DO_E) {
    float s = 0, s2 = 0;
#pragma unroll 4
    for (int r = 0; r < 32; ++r) {
      int blk = r * 256 + t;
      s += bn_ps[(size_t)blk * H_ + h];
      s2 += bn_ps2[(size_t)blk * H_ + h];
    }
    r1[t] = s; r2[t] = s2; __syncthreads();
    for (int st = 128; st > 0; st >>= 1) {
      if (t < st) { r1[t] += r1[t + st]; r2[t] += r2[t + st]; }
      __syncthreads();
    }
    if (t == 0) {
      const float inv = 1.f / 262144.f;
      float mu = r1[0] * inv;
      float var = r2[0] * inv - mu * mu;
      mu_rs[h] = mu;
      mu_rs[H_ + h] = rsqrtf(var + 1e-5f);
    }
    __syncthreads();
  }
  // x update: x += relu(BN(Unx + agg))
  float xt[4];
  float s = 0, s2 = 0;
#pragma unroll
  for (int r = 0; r < 4; ++r) {
    int idx = r * 256 + t;
    float sN = 0, sD = 0;
#pragma unroll
    for (int jq = 0; jq < NJQ_; ++jq) {
      size_t o = ((size_t)jq * BV_ + idx) * H_ + h;
      sN += aggN[o]; sD += aggD[o];
    }
    float v = Unx[(size_t)idx * H_ + h] + sN / (sD + 1e-20f);
    xt[r] = v; s += v; s2 += v * v;
  }
  r1[t] = s; r2[t] = s2; __syncthreads();
  for (int st = 128; st > 0; st >>= 1) {
    if (t < st) { r1[t] += r1[t + st]; r2[t] += r2[t + st]; }
    __syncthreads();
  }
  float mu = r1[0] * (1.f / 1024.f);
  float var = r2[0] * (1.f / 1024.f) - mu * mu;
  float rs = rsqrtf(var + 1e-5f);
  float g = g_x[h], bb = bx_bn[h];
#pragma unroll
  for (int r = 0; r < 4; ++r) {
    int idx = r * 256 + t;
    size_t o = (size_t)idx * H_ + h;
    float v = g * (xt[r] - mu) * rs + bb;
    if (v > 0.f) x[o] += v;
  }
}

// ---------------- readout ----------------
__global__ void k6_readout(const float* __restrict__ x, const float* __restrict__ W1,
                           const float* __restrict__ b1, const float* __restrict__ W2,
                           float* __restrict__ out_acc) {
  __shared__ float xs[H_];
  __shared__ float red[H_];
  int bi = blockIdx.x, h = threadIdx.x;
  int b = bi >> 8;
  xs[h] = x[(size_t)bi * H_ + h];
  __syncthreads();
  float a = b1[h];
#pragma unroll 8
  for (int k = 0; k < H_; ++k) a += xs[k] * W1[k * H_ + h];
  a = fmaxf(a, 0.f) * W2[h];
  red[h] = a; __syncthreads();
  for (int s = 64; s > 0; s >>= 1) {
    if (h < s) red[h] += red[h + s];
    __syncthreads();
  }
  if (h == 0) atomicAdd(&out_acc[b], red[0]);
}

__global__ void k7_final(const float* __restrict__ out_acc,
                         const float* __restrict__ b_mlp2, float* __restrict__ out) {
  int t = threadIdx.x;
  if (t < 4) out[t] = out_acc[t] * (1.f / 256.f) + b_mlp2[0];
}

extern "C" void kernel_launch(void* const* d_in, const int* in_sizes, int n_in,
                              void* d_out, int out_size, void* d_ws, size_t ws_size,
                              hipStream_t stream) {
  (void)in_sizes; (void)out_size; (void)ws_size;
  const int off = n_in - 26;  // tolerate pruned x_edges
  const float* x_ev    = (const float*)d_in[off + 0];
  const float* x_coord = (const float*)d_in[off + 1];
  const float* x_tour  = (const float*)d_in[off + 2];
  const float* x_btour = (const float*)d_in[off + 3];
  const float* W_node  = (const float*)d_in[off + 4];
  const float* b_node  = (const float*)d_in[off + 5];
  const float* W_eval  = (const float*)d_in[off + 6];
  const float* b_eval  = (const float*)d_in[off + 7];
  const float* W_ecat  = (const float*)d_in[off + 8];
  const float* b_ecat  = (const float*)d_in[off + 9];
  const float* Ue      = (const float*)d_in[off + 10];
  const float* bUe     = (const float*)d_in[off + 11];
  const float* Ve      = (const float*)d_in[off + 12];
  const float* bVe     = (const float*)d_in[off + 13];
  const float* Un      = (const float*)d_in[off + 14];
  const float* bUn     = (const float*)d_in[off + 15];
  const float* Vn      = (const float*)d_in[off + 16];
  const float* bVn     = (const float*)d_in[off + 17];
  const float* g_e     = (const float*)d_in[off + 18];
  const float* be_bn   = (const float*)d_in[off + 19];
  const float* g_x     = (const float*)d_in[off + 20];
  const float* bx_bn   = (const float*)d_in[off + 21];
  const float* W_mlp1  = (const float*)d_in[off + 22];
  const float* b_mlp1  = (const float*)d_in[off + 23];
  const float* W_mlp2  = (const float*)d_in[off + 24];
  const float* b_mlp2  = (const float*)d_in[off + 25];

  char* ws = (char*)d_ws;
  float*  x      = (float*)(ws + 0x0000000);
  float2* VV     = (float2*)(ws + 0x0080000);   // 1 MB
  float*  Unx    = (float*)(ws + 0x0180000);
  float*  aggN   = (float*)(ws + 0x0200000);    // 4 MB [8][BV][H]
  float*  aggD   = (float*)(ws + 0x0600000);    // 4 MB
  float*  bn_ps  = (float*)(ws + 0x0A00000);    // 4 MB
  float*  bn_ps2 = (float*)(ws + 0x0E00000);    // 4 MB
  float*  mu_rs  = (float*)(ws + 0x1200000);
  float*  out_acc= (float*)(ws + 0x1200400);
  bhalf*  UeT_g  = (bhalf*)(ws + 0x1201000);    // 96 KB
  bhalf*  e      = (bhalf*)(ws + 0x1220000);                 // 64 MiB
  bhalf*  e_tmp  = (bhalf*)(ws + 0x1220000 + 0x4000000);     // 64 MiB

  k_init<<<1, 64, 0, stream>>>(out_acc);
  k_prep<<<NL_, 256, 0, stream>>>(Ue, UeT_g);
  k0_x<<<BV_, H_, 0, stream>>>(x_coord, W_node, b_node, x);
  k0_e<<<BV_, 256, 0, stream>>>(x_ev, x_tour, x_btour, W_eval, b_eval, W_ecat, b_ecat, e);

  const int G2 = BV_ * NJQ_;
  // layer 0
  k1_xproj<<<BV_, H_, 0, stream>>>(x, Ve, bVe, Vn, bVn, Un, bUn, VV, Unx);
  k2_edge<0><<<G2, 256, 0, stream>>>(e, e_tmp, (bhalf*)0, UeT_g, bUe, VV,
                                     (float*)0, (float*)0, (float*)0,
                                     aggN, aggD, bn_ps, bn_ps2);
  k34<true><<<H_, 256, 0, stream>>>(bn_ps, bn_ps2, mu_rs, x, Unx, aggN, aggD, g_x, bx_bn);
  // layer 1 (staging fuses e += relu(BN_l0(e_tmp)))
  k1_xproj<<<BV_, H_, 0, stream>>>(x, Ve + H_*H_, bVe + H_, Vn + H_*H_, bVn + H_,
                                   Un + H_*H_, bUn + H_, VV, Unx);
  k2_edge<1><<<G2, 256, 0, stream>>>(e, e_tmp, e_tmp, UeT_g + H_*H_, bUe + H_, VV,
                                     mu_rs, g_e, be_bn,
                                     aggN, aggD, bn_ps, bn_ps2);
  k34<true><<<H_, 256, 0, stream>>>(bn_ps, bn_ps2, mu_rs, x, Unx, aggN, aggD,
                                    g_x + H_, bx_bn + H_);
  // layer 2 (staging fuses e += relu(BN_l1(e_tmp)); e/e_tmp outputs dead)
  k1_xproj<<<BV_, H_, 0, stream>>>(x, Ve + 2*H_*H_, bVe + 2*H_, Vn + 2*H_*H_, bVn + 2*H_,
                                   Un + 2*H_*H_, bUn + 2*H_, VV, Unx);
  k2_edge<2><<<G2, 256, 0, stream>>>(e, (bhalf*)0, e_tmp, UeT_g + 2*H_*H_, bUe + 2*H_, VV,
                                     mu_rs, g_e + H_, be_bn + H_,
                                     aggN, aggD, bn_ps, bn_ps2);
  k34<false><<<H_, 256, 0, stream>>>(bn_ps, bn_ps2, mu_rs, x, Unx, aggN, aggD,
                                     g_x + 2*H_, bx_bn + 2*H_);

  k6_readout<<<BV_, H_, 0, stream>>>(x, W_mlp1, b_mlp1, W_mlp2, out_acc);
  k7_final<<<1, 64, 0, stream>>>(out_acc, b_mlp2, (float*)d_out);
}